// Round 4
// baseline (39.825 us; speedup 1.0000x reference)
//
#include <hip/hip_runtime.h>
#include <math.h>

namespace {

constexpr int kNA      = 3;
constexpr int kGS      = 13;
constexpr int kAttrs   = 85;           // 5 + 80 classes
constexpr int kSpatial = kGS * kGS;    // 169
constexpr int kCells   = 512 * kNA * kSpatial;  // 259,584
constexpr float kStrideF = 32.0f;      // 416 / 13

constexpr int kBlockThreads  = 256;                 // 4 waves
constexpr int kThreadsPerCell = 4;
constexpr int kCellsPerBlock = kBlockThreads / kThreadsPerCell;  // 64
constexpr int kSmemFloats    = kCellsPerBlock * kAttrs;          // 5,440 = 21,760 B
constexpr int kSmemFloat4    = kSmemFloats / 4;                  // 1,360
constexpr int kMaxAttrsPerThread = 22;              // q=0 has 22, q=1..3 have 21

__device__ __forceinline__ float fsigmoid(float x) {
    return 1.0f / (1.0f + __expf(-x));
}

__global__ __launch_bounds__(kBlockThreads) void yolo_head_kernel(const float* __restrict__ x,
                                                                  float* __restrict__ out) {
    __shared__ float smem[kSmemFloats];

    const int tid  = threadIdx.x;
    const int q    = tid & 3;          // attr-slice within the cell's 4-lane group
    const int cl   = tid >> 2;         // cell-local index (0..63)
    const int cell = blockIdx.x * kCellsPerBlock + cl;   // grid sized exactly

    const int s  = cell % kSpatial;    // i*13 + j
    const int ba = cell / kSpatial;    // b*3 + a
    const int a  = ba % kNA;

    // x[b, a*85 + c, i, j] -> base + c*169. Thread q loads attrs c = q + 4i.
    // Per load instruction the wave covers 4 attr planes x 16 consecutive s
    // = 4 fully-used 64B segments.
    const float* __restrict__ xp = x + (size_t)ba * kAttrs * kSpatial + s;

    float v[kMaxAttrsPerThread];
#pragma unroll
    for (int i = 0; i < kMaxAttrsPerThread; ++i) {
        const int c = q + 4 * i;
        if (c < kAttrs) v[i] = xp[(size_t)c * kSpatial];
    }

    // ---- softmax over class attrs (c >= 5) split across the 4-lane group ----
    float m = -INFINITY;
#pragma unroll
    for (int i = 0; i < kMaxAttrsPerThread; ++i) {
        const int c = q + 4 * i;
        if (c >= 5 && c < kAttrs) m = fmaxf(m, v[i]);
    }
    m = fmaxf(m, __shfl_xor(m, 1, 64));
    m = fmaxf(m, __shfl_xor(m, 2, 64));

    float sum = 0.0f;
#pragma unroll
    for (int i = 0; i < kMaxAttrsPerThread; ++i) {
        const int c = q + 4 * i;
        if (c >= 5 && c < kAttrs) {
            v[i] = __expf(v[i] - m);
            sum += v[i];
        }
    }
    sum += __shfl_xor(sum, 1, 64);
    sum += __shfl_xor(sum, 2, 64);
    const float inv = 1.0f / sum;

    // ---- stage transformed outputs into LDS (cell-major, stride 85) ----
    float* __restrict__ sp = smem + cl * kAttrs;

    if (q == 0) {
        const float jf = (float)(s % kGS);                 // grid_x
        sp[0] = (fsigmoid(v[0]) + jf) * kStrideF;          // bx   (attr 0)
        sp[4] = fsigmoid(v[1]);                            // conf (attr 4)
    } else if (q == 1) {
        const float if_ = (float)(s / kGS);                // grid_y
        sp[1] = (fsigmoid(v[0]) + if_) * kStrideF;         // by   (attr 1)
    } else if (q == 2) {
        const float aw = (a == 0) ? 116.0f : (a == 1) ? 156.0f : 373.0f;
        sp[2] = __expf(v[0]) * aw;                         // bw   (attr 2)
    } else {
        const float ah = (a == 0) ? 90.0f : (a == 1) ? 198.0f : 326.0f;
        sp[3] = __expf(v[0]) * ah;                         // bh   (attr 3)
    }
#pragma unroll
    for (int i = 0; i < kMaxAttrsPerThread; ++i) {
        const int c = q + 4 * i;
        if (c >= 5 && c < kAttrs) sp[c] = v[i] * inv;
    }

    __syncthreads();

    // ---- coalesced float4 copy of the block's contiguous output region ----
    const float4* __restrict__ s4 = (const float4*)smem;
    float4* __restrict__ out4 = (float4*)(out + (size_t)blockIdx.x * kSmemFloats);
#pragma unroll 2
    for (int t = tid; t < kSmemFloat4; t += kBlockThreads) {
        out4[t] = s4[t];
    }
}

}  // namespace

extern "C" void kernel_launch(void* const* d_in, const int* in_sizes, int n_in,
                              void* d_out, int out_size, void* d_ws, size_t ws_size,
                              hipStream_t stream) {
    const float* x = (const float*)d_in[0];
    float* out = (float*)d_out;
    const int blocks = kCells / kCellsPerBlock;  // 4056 exactly
    yolo_head_kernel<<<blocks, kBlockThreads, 0, stream>>>(x, out);
}